// Round 9
// baseline (33.134 us; speedup 1.0000x reference)
//
#include <hip/hip_runtime.h>

// EnergyPool2d: N=16, C=64, H=W=128, 3x3 windows stride 1 -> Ho=Wo=126.
// +1 at first-argmax flat index, -1 at first-argmin flat index per window.
// R9 = R8 half-plane structure (512 thr, 32KB LDS count, ownership guard)
// + separable h-stat math (R6, correct) + __launch_bounds__(512,4) so the
// 48-float tile lives in registers (R6 regressed purely from the 32-VGPR
// cap forcing scratch spill: WRITE_SIZE was 267MB; must be exactly 64MB).
// One 4x4-window tile per thread: 6 rows x 8 cols input, 12 float4 loads,
// 24 h-stats reused by 16 windows.

#define HH 128
#define WW 128
#define HO 126
#define WO 126
#define PLANE (HH * WW)     // 16384
#define HROWS 64
#define HPLANE (HROWS * WW) // 8192
#define NPLANES (16 * 64)   // 1024
#define BLOCK 512

__global__ __launch_bounds__(BLOCK, 4)
void energy_pool2d_kernel(const float* __restrict__ x, float* __restrict__ out) {
    __shared__ int cnt[HPLANE]; // 32 KB

    const int tid = threadIdx.x;
    const int plane = blockIdx.x >> 1;
    const int half = blockIdx.x & 1;
    const float* __restrict__ xp = x + (size_t)plane * PLANE;

    // Zero the LDS half-plane.
    int4* c4 = (int4*)cnt;
#pragma unroll
    for (int i = 0; i < HPLANE / 4 / BLOCK; ++i)
        c4[tid + i * BLOCK] = make_int4(0, 0, 0, 0);
    __syncthreads();

    const int row0 = half ? 62 : 0;   // first window row of this half
    const int bias = half * HPLANE;

    // One 4x4-window tile per thread: 16 row-tiles x 32 col-tiles = 512.
    const int rt = tid >> 5;          // 0..15
    const int ct = tid & 31;          // 0..31
    const int wr0 = row0 + rt * 4;    // window rows wr0..wr0+3
    const int j0 = ct * 4;            // window cols j0..j0+3 (ct=31: 2 cols)
    const float* __restrict__ p = xp + wr0 * WW + j0;
    const bool cfull = (ct < 31);

    // Load 6 rows x 8 cols (right half zeroed at the right edge; edge tile
    // only uses cols 124..127, keeps all loads in-bounds).
    float r[6][8];
#pragma unroll
    for (int q = 0; q < 6; ++q) {
        const float4 a = *(const float4*)(p + q * WW);
        r[q][0] = a.x; r[q][1] = a.y; r[q][2] = a.z; r[q][3] = a.w;
    }
    if (cfull) {
#pragma unroll
        for (int q = 0; q < 6; ++q) {
            const float4 b = *(const float4*)(p + q * WW + 4);
            r[q][4] = b.x; r[q][5] = b.y; r[q][6] = b.z; r[q][7] = b.w;
        }
    } else {
#pragma unroll
        for (int q = 0; q < 6; ++q)
            r[q][4] = r[q][5] = r[q][6] = r[q][7] = 0.f;
    }

    const int base = wr0 * WW + j0;   // plane-flat index of tile origin

#pragma unroll
    for (int o = 0; o < 4; ++o) {     // window col-offset within tile
        const bool oval = (o < 2) || cfull;
        // h-stats for 6 rows at this offset: first-occurrence 1x3
        // argmax/argmin via max3/min3 + backward equality select.
        float hM[6], hm[6];
        int hA[6], ha[6];
#pragma unroll
        for (int q = 0; q < 6; ++q) {
            const float v0 = r[q][o], v1 = r[q][o + 1], v2 = r[q][o + 2];
            const int f0 = q * WW + o;
            const float M = fmaxf(fmaxf(v0, v1), v2);  // v_max3_f32
            int A = f0 + 2;
            if (v1 == M) A = f0 + 1;
            if (v0 == M) A = f0;                       // first col == M
            const float m = fminf(fminf(v0, v1), v2);  // v_min3_f32
            int a = f0 + 2;
            if (v1 == m) a = f0 + 1;
            if (v0 == m) a = f0;
            hM[q] = M; hA[q] = A; hm[q] = m; ha[q] = a;
        }
#pragma unroll
        for (int wr = 0; wr < 4; ++wr) { // window row-offset within tile
            if (oval) {
                // Vertical first-occurrence via backward equality select.
                const float WM =
                    fmaxf(fmaxf(hM[wr], hM[wr + 1]), hM[wr + 2]);
                int wA = hA[wr + 2];
                if (hM[wr + 1] == WM) wA = hA[wr + 1];
                if (hM[wr] == WM) wA = hA[wr];
                const float Wm =
                    fminf(fminf(hm[wr], hm[wr + 1]), hm[wr + 2]);
                int wa = ha[wr + 2];
                if (hm[wr + 1] == Wm) wa = ha[wr + 1];
                if (hm[wr] == Wm) wa = ha[wr];
                // Ownership guard doubles as seam resolution between halves.
                const int iM = base + wA - bias;
                if ((unsigned)iM < HPLANE) atomicAdd(&cnt[iM], 1);
                const int im = base + wa - bias;
                if ((unsigned)im < HPLANE) atomicAdd(&cnt[im], -1);
            }
        }
    }
    __syncthreads();

    // Coalesced writeout of this half (fully overwritten -> no pre-zero).
    float4* __restrict__ o4 = (float4*)(out + (size_t)plane * PLANE + bias);
#pragma unroll
    for (int i = 0; i < HPLANE / 4 / BLOCK; ++i) {
        const int4 ci = c4[tid + i * BLOCK];
        o4[tid + i * BLOCK] =
            make_float4((float)ci.x, (float)ci.y, (float)ci.z, (float)ci.w);
    }
}

extern "C" void kernel_launch(void* const* d_in, const int* in_sizes, int n_in,
                              void* d_out, int out_size, void* d_ws, size_t ws_size,
                              hipStream_t stream) {
    const float* x = (const float*)d_in[0];
    float* out = (float*)d_out;
    energy_pool2d_kernel<<<NPLANES * 2, BLOCK, 0, stream>>>(x, out);
}